// Round 1
// baseline (1350.363 us; speedup 1.0000x reference)
//
#include <hip/hip_runtime.h>
#include <cstdint>
#include <cstddef>

// SimpleGCN: h = x@W1+b1; 3x GCNConv(sym-norm adj w/ self loops); sigmoid(h@W2+b2)
// N=100000, d=128, E=1.6M. All fp32.
//
// Structure:
//  1. deg histogram (float atomics) + in-degree counts (int atomics)
//  2. single-block scan -> CSR row_ptr (by destination)
//  3. scatter edges into CSR (esrc, enorm), norm precomputed once (layer-invariant)
//  4. per layer: gemm128 (W in LDS, 4x8 reg tile), aggregate (1 wave per dest node)
//  5. gemv + sigmoid

__global__ void init_kernel(float* __restrict__ deg, int* __restrict__ cnt, int n) {
    int i = blockIdx.x * blockDim.x + threadIdx.x;
    if (i < n) { deg[i] = 1.0f; cnt[i] = 0; }   // deg starts at 1.0 = self-loop weight
}

__global__ void histo_kernel(const int* __restrict__ col, const float* __restrict__ ew,
                             float* __restrict__ deg, int* __restrict__ cnt, int E) {
    int e = blockIdx.x * blockDim.x + threadIdx.x;
    if (e < E) {
        int c = col[e];
        atomicAdd(&deg[c], ew[e]);
        atomicAdd(&cnt[c], 1);
    }
}

// Exclusive scan of cnt[0..n) -> row_ptr[0..n]; single block of 1024 threads.
__global__ __launch_bounds__(1024) void scan_kernel(const int* __restrict__ cnt,
                                                    int* __restrict__ row_ptr, int n) {
    __shared__ int sums[1024];
    int tid = threadIdx.x;
    int per = (n + 1023) >> 10;
    int start = tid * per;
    int end   = min(start + per, n);
    int s = 0;
    for (int i = start; i < end; ++i) s += cnt[i];
    sums[tid] = s;
    __syncthreads();
    // Hillis-Steele inclusive scan (read-then-barrier-then-write is race-free)
    for (int off = 1; off < 1024; off <<= 1) {
        int v = (tid >= off) ? sums[tid - off] : 0;
        __syncthreads();
        sums[tid] += v;
        __syncthreads();
    }
    int run = (tid == 0) ? 0 : sums[tid - 1];
    for (int i = start; i < end; ++i) { row_ptr[i] = run; run += cnt[i]; }
    if (tid == 1023) row_ptr[n] = sums[1023];
}

__global__ void prep_kernel(const float* __restrict__ deg, float* __restrict__ dinv,
                            const int* __restrict__ row_ptr, int* __restrict__ cursor, int n) {
    int i = blockIdx.x * blockDim.x + threadIdx.x;
    if (i < n) {
        dinv[i]   = rsqrtf(deg[i]);   // deg >= 1 always (self loop)
        cursor[i] = row_ptr[i];
    }
}

__global__ void scatter_kernel(const int* __restrict__ row, const int* __restrict__ col,
                               const float* __restrict__ ew, const float* __restrict__ dinv,
                               int* __restrict__ cursor, int* __restrict__ esrc,
                               float* __restrict__ enorm, int E) {
    int e = blockIdx.x * blockDim.x + threadIdx.x;
    if (e < E) {
        int r = row[e], c = col[e];
        int pos = atomicAdd(&cursor[c], 1);
        esrc[pos]  = r;
        enorm[pos] = dinv[r] * ew[e] * dinv[c];
    }
}

// C[n x 128] = A[n x 128] @ W[128 x 128] (+ bias). W staged in LDS (64 KB),
// A read from global (L1-cached; 16x redundancy within block). 64 rows/block,
// each thread computes a 4-row x 8-col register tile.
__global__ __launch_bounds__(256) void gemm128_kernel(const float* __restrict__ A,
                                                      const float* __restrict__ W,
                                                      const float* __restrict__ bias,
                                                      float* __restrict__ C, int n) {
    __shared__ float Wl[128 * 128];
    int tid = threadIdx.x;
#pragma unroll
    for (int i = 0; i < 64; ++i) Wl[i * 256 + tid] = W[i * 256 + tid];
    __syncthreads();

    int row0 = blockIdx.x * 64;
    int tr = (tid & 15) * 4;     // base row in tile (4 consecutive rows)
    int tc = (tid >> 4) * 8;     // base col (8 consecutive cols)

    // clamp row indices for safe OOB loads; stores are guarded exactly
    size_t r0 = (size_t)min(row0 + tr + 0, n - 1);
    size_t r1 = (size_t)min(row0 + tr + 1, n - 1);
    size_t r2 = (size_t)min(row0 + tr + 2, n - 1);
    size_t r3 = (size_t)min(row0 + tr + 3, n - 1);

    float acc[4][8];
#pragma unroll
    for (int r = 0; r < 4; ++r)
#pragma unroll
        for (int c = 0; c < 8; ++c) acc[r][c] = 0.0f;

    for (int k = 0; k < 128; k += 4) {
        float av[4][4];
        *(float4*)av[0] = *(const float4*)(A + r0 * 128 + k);
        *(float4*)av[1] = *(const float4*)(A + r1 * 128 + k);
        *(float4*)av[2] = *(const float4*)(A + r2 * 128 + k);
        *(float4*)av[3] = *(const float4*)(A + r3 * 128 + k);
#pragma unroll
        for (int kk = 0; kk < 4; ++kk) {
            float wv[8];
            *(float4*)&wv[0] = *(const float4*)&Wl[(k + kk) * 128 + tc];
            *(float4*)&wv[4] = *(const float4*)&Wl[(k + kk) * 128 + tc + 4];
#pragma unroll
            for (int r = 0; r < 4; ++r)
#pragma unroll
                for (int c = 0; c < 8; ++c) acc[r][c] += av[r][kk] * wv[c];
        }
    }

    float bv[8];
    if (bias) {
        *(float4*)&bv[0] = *(const float4*)&bias[tc];
        *(float4*)&bv[4] = *(const float4*)&bias[tc + 4];
    } else {
#pragma unroll
        for (int c = 0; c < 8; ++c) bv[c] = 0.0f;
    }

#pragma unroll
    for (int r = 0; r < 4; ++r) {
        int gr = row0 + tr + r;
        if (gr < n) {
            float o[8];
#pragma unroll
            for (int c = 0; c < 8; ++c) o[c] = acc[r][c] + bv[c];
            *(float4*)(C + (size_t)gr * 128 + tc)     = *(float4*)&o[0];
            *(float4*)(C + (size_t)gr * 128 + tc + 4) = *(float4*)&o[4];
        }
    }
}

// One wave (64 lanes x float2 = 128 feats) per destination node.
// out[i] = bias + dinv[i]^2 * t[i] + sum_e norm_e * t[src_e]
__global__ __launch_bounds__(256) void aggregate_kernel(const float* __restrict__ t,
                                                        const int* __restrict__ row_ptr,
                                                        const int* __restrict__ esrc,
                                                        const float* __restrict__ enorm,
                                                        const float* __restrict__ dinv,
                                                        const float* __restrict__ bias,
                                                        float* __restrict__ out, int n) {
    int wid  = (int)((blockIdx.x * (size_t)blockDim.x + threadIdx.x) >> 6);
    int lane = threadIdx.x & 63;
    if (wid >= n) return;
    const float2* tv = (const float2*)t;

    float di = dinv[wid];
    float sn = di * di;                       // self-loop norm = 1/deg
    float2 ts = tv[(size_t)wid * 64 + lane];
    float accx = sn * ts.x, accy = sn * ts.y;

    int start = row_ptr[wid], end = row_ptr[wid + 1];
    for (int base = start; base < end; base += 64) {
        int rem = end - base;
        int s = 0; float w = 0.0f;
        if (lane < rem) { s = esrc[base + lane]; w = enorm[base + lane]; }
        int m = rem < 64 ? rem : 64;
        for (int j = 0; j < m; ++j) {
            int   sj = __shfl(s, j);
            float wj = __shfl(w, j);
            float2 v = tv[(size_t)sj * 64 + lane];
            accx += wj * v.x;
            accy += wj * v.y;
        }
    }
    float2 bb = ((const float2*)bias)[lane];
    float2 o; o.x = accx + bb.x; o.y = accy + bb.y;
    ((float2*)out)[(size_t)wid * 64 + lane] = o;
}

// out[i] = sigmoid(dot(h[i], W2) + b2); one wave per row.
__global__ __launch_bounds__(256) void gemv_sigmoid_kernel(const float* __restrict__ h,
                                                           const float* __restrict__ W2,
                                                           const float* __restrict__ b2,
                                                           float* __restrict__ out, int n) {
    int wid  = (int)((blockIdx.x * (size_t)blockDim.x + threadIdx.x) >> 6);
    int lane = threadIdx.x & 63;
    if (wid >= n) return;
    float2 hv = ((const float2*)h)[(size_t)wid * 64 + lane];
    float2 wv = ((const float2*)W2)[lane];
    float d = hv.x * wv.x + hv.y * wv.y;
#pragma unroll
    for (int off = 32; off > 0; off >>= 1) d += __shfl_down(d, off);
    if (lane == 0) out[wid] = 1.0f / (1.0f + expf(-(d + b2[0])));
}

extern "C" void kernel_launch(void* const* d_in, const int* in_sizes, int n_in,
                              void* d_out, int out_size, void* d_ws, size_t ws_size,
                              hipStream_t stream) {
    const float* x  = (const float*)d_in[0];
    const int*   ei = (const int*)d_in[1];   // [2, E] int32
    const float* ea = (const float*)d_in[2]; // [E]
    const float* W1 = (const float*)d_in[3];
    const float* b1 = (const float*)d_in[4];
    const float* Wg = (const float*)d_in[5]; // [3,128,128]
    const float* bg = (const float*)d_in[6]; // [3,128]
    const float* W2 = (const float*)d_in[7]; // [128]
    const float* b2 = (const float*)d_in[8]; // [1]

    const int N = in_sizes[0] / 128;
    const int E = in_sizes[2];
    const int* row = ei;
    const int* col = ei + E;

    // workspace layout (all offsets 16B-aligned)
    char* p = (char*)d_ws;
    float* hbuf = (float*)p; p += (size_t)N * 128 * 4;
    float* tbuf = (float*)p; p += (size_t)N * 128 * 4;
    float* deg  = (float*)p; p += (size_t)N * 4;
    float* dinv = (float*)p; p += (size_t)N * 4;
    int* cnt     = (int*)p;  p += (size_t)N * 4;
    int* row_ptr = (int*)p;  p += (size_t)(N + 1) * 4 + 12;
    int* cursor  = (int*)p;  p += (size_t)N * 4;
    int* esrc    = (int*)p;  p += (size_t)E * 4;
    float* enorm = (float*)p;

    dim3 b256(256);
    init_kernel   <<<(N + 255) / 256, b256, 0, stream>>>(deg, cnt, N);
    histo_kernel  <<<(E + 255) / 256, b256, 0, stream>>>(col, ea, deg, cnt, E);
    scan_kernel   <<<1, 1024, 0, stream>>>(cnt, row_ptr, N);
    prep_kernel   <<<(N + 255) / 256, b256, 0, stream>>>(deg, dinv, row_ptr, cursor, N);
    scatter_kernel<<<(E + 255) / 256, b256, 0, stream>>>(row, col, ea, dinv, cursor, esrc, enorm, E);

    int gemm_blocks = (N + 63) / 64;
    int wave_blocks = (int)(((size_t)N * 64 + 255) / 256);

    gemm128_kernel<<<gemm_blocks, b256, 0, stream>>>(x, W1, b1, hbuf, N);
    for (int l = 0; l < 3; ++l) {
        gemm128_kernel  <<<gemm_blocks, b256, 0, stream>>>(hbuf, Wg + (size_t)l * 128 * 128,
                                                           nullptr, tbuf, N);
        aggregate_kernel<<<wave_blocks, b256, 0, stream>>>(tbuf, row_ptr, esrc, enorm, dinv,
                                                           bg + (size_t)l * 128, hbuf, N);
    }
    gemv_sigmoid_kernel<<<wave_blocks, b256, 0, stream>>>(hbuf, W2, b2, (float*)d_out, N);
}

// Round 2
// 1116.615 us; speedup vs baseline: 1.2093x; 1.2093x over previous
//
#include <hip/hip_runtime.h>
#include <cstdint>
#include <cstddef>

// SimpleGCN: h = x@W1+b1; 3x GCNConv(sym-norm adj w/ self loops); sigmoid(h@W2+b2)
// N=100000, d=128, E=1.6M.
// R2: multi-block scan (was 162us single-block), bf16 message buffer (halves
// gather traffic in aggregate), final gemv+sigmoid fused into layer-3 aggregate.

// ---------- bf16 helpers (manual packing: low 16 bits = element 0) ----------
__device__ __forceinline__ unsigned f2bf(float f) {      // RNE float->bf16 bits
    unsigned u = __float_as_uint(f);
    u += 0x7fffu + ((u >> 16) & 1u);
    return u >> 16;
}
__device__ __forceinline__ float bf_lo(unsigned p) { return __uint_as_float(p << 16); }
__device__ __forceinline__ float bf_hi(unsigned p) { return __uint_as_float(p & 0xffff0000u); }

// ---------- degree histogram ----------
__global__ void init_kernel(float* __restrict__ deg, int* __restrict__ cnt, int n) {
    int i = blockIdx.x * blockDim.x + threadIdx.x;
    if (i < n) { deg[i] = 1.0f; cnt[i] = 0; }   // deg starts at 1.0 = self-loop weight
}

__global__ void histo_kernel(const int* __restrict__ col, const float* __restrict__ ew,
                             float* __restrict__ deg, int* __restrict__ cnt, int E) {
    int e = blockIdx.x * blockDim.x + threadIdx.x;
    if (e < E) {
        int c = col[e];
        atomicAdd(&deg[c], ew[e]);
        atomicAdd(&cnt[c], 1);
    }
}

// ---------- 3-phase exclusive scan: cnt[0..n) -> row_ptr[0..n], cursor ----------
// phase 1: per-block (1024-elem chunk) sums
__global__ __launch_bounds__(256) void scan1_kernel(const int* __restrict__ cnt,
                                                    int* __restrict__ bsum, int n) {
    __shared__ int s[256];
    int b = blockIdx.x, t = threadIdx.x;
    int base = b * 1024 + t * 4;
    int v0 = 0, v1 = 0, v2 = 0, v3 = 0;
    if (base + 3 < n) {
        int4 q = *(const int4*)(cnt + base);
        v0 = q.x; v1 = q.y; v2 = q.z; v3 = q.w;
    } else {
        if (base + 0 < n) v0 = cnt[base + 0];
        if (base + 1 < n) v1 = cnt[base + 1];
        if (base + 2 < n) v2 = cnt[base + 2];
        if (base + 3 < n) v3 = cnt[base + 3];
    }
    s[t] = v0 + v1 + v2 + v3;
    __syncthreads();
    for (int off = 128; off > 0; off >>= 1) {
        if (t < off) s[t] += s[t + off];
        __syncthreads();
    }
    if (t == 0) bsum[b] = s[0];
}

// phase 2: exclusive scan of block sums (nblk <= 256) in-place
__global__ __launch_bounds__(256) void scan2_kernel(int* __restrict__ bsum, int nblk) {
    __shared__ int s[256];
    int t = threadIdx.x;
    int v = (t < nblk) ? bsum[t] : 0;
    s[t] = v;
    __syncthreads();
    for (int off = 1; off < 256; off <<= 1) {
        int u = (t >= off) ? s[t - off] : 0;
        __syncthreads();
        s[t] += u;
        __syncthreads();
    }
    if (t < nblk) bsum[t] = s[t] - v;   // exclusive
}

// phase 3: per-block local scan + block offset -> row_ptr & cursor
__global__ __launch_bounds__(256) void scan3_kernel(const int* __restrict__ cnt,
                                                    const int* __restrict__ boff,
                                                    int* __restrict__ row_ptr,
                                                    int* __restrict__ cursor,
                                                    int n, int nblk) {
    __shared__ int s[256];
    int b = blockIdx.x, t = threadIdx.x;
    int base = b * 1024 + t * 4;
    int v0 = 0, v1 = 0, v2 = 0, v3 = 0;
    if (base + 3 < n) {
        int4 q = *(const int4*)(cnt + base);
        v0 = q.x; v1 = q.y; v2 = q.z; v3 = q.w;
    } else {
        if (base + 0 < n) v0 = cnt[base + 0];
        if (base + 1 < n) v1 = cnt[base + 1];
        if (base + 2 < n) v2 = cnt[base + 2];
        if (base + 3 < n) v3 = cnt[base + 3];
    }
    s[t] = v0 + v1 + v2 + v3;
    __syncthreads();
    for (int off = 1; off < 256; off <<= 1) {
        int u = (t >= off) ? s[t - off] : 0;
        __syncthreads();
        s[t] += u;
        __syncthreads();
    }
    int run = boff[b] + ((t == 0) ? 0 : s[t - 1]);
    if (base + 0 < n) { row_ptr[base + 0] = run; cursor[base + 0] = run; run += v0; }
    if (base + 1 < n) { row_ptr[base + 1] = run; cursor[base + 1] = run; run += v1; }
    if (base + 2 < n) { row_ptr[base + 2] = run; cursor[base + 2] = run; run += v2; }
    if (base + 3 < n) { row_ptr[base + 3] = run; cursor[base + 3] = run; run += v3; }
    if (b == nblk - 1 && t == 255) row_ptr[n] = boff[b] + s[255];
}

__global__ void prep_kernel(const float* __restrict__ deg, float* __restrict__ dinv, int n) {
    int i = blockIdx.x * blockDim.x + threadIdx.x;
    if (i < n) dinv[i] = rsqrtf(deg[i]);   // deg >= 1 always (self loop)
}

__global__ void scatter_kernel(const int* __restrict__ row, const int* __restrict__ col,
                               const float* __restrict__ ew, const float* __restrict__ dinv,
                               int* __restrict__ cursor, int* __restrict__ esrc,
                               float* __restrict__ enorm, int E) {
    int e = blockIdx.x * blockDim.x + threadIdx.x;
    if (e < E) {
        int r = row[e], c = col[e];
        int pos = atomicAdd(&cursor[c], 1);
        esrc[pos]  = r;
        enorm[pos] = dinv[r] * ew[e] * dinv[c];
    }
}

// ---------- GEMM: C[n x 128] = A[n x 128] @ W[128 x 128] (+ bias) ----------
// W staged in LDS (64 KB). 64 rows/block, 4-row x 8-col register tile/thread.
// BF16OUT: C is packed bf16 (2 per dword), row stride 64 dwords.
template<bool BF16OUT>
__global__ __launch_bounds__(256) void gemm128_kernel(const float* __restrict__ A,
                                                      const float* __restrict__ W,
                                                      const float* __restrict__ bias,
                                                      void* __restrict__ C, int n) {
    __shared__ float Wl[128 * 128];
    int tid = threadIdx.x;
    {
        const float4* Wv = (const float4*)W;
        float4* Wlv = (float4*)Wl;
#pragma unroll
        for (int i = 0; i < 16; ++i) Wlv[i * 256 + tid] = Wv[i * 256 + tid];
    }
    __syncthreads();

    int row0 = blockIdx.x * 64;
    int tr = (tid & 15) * 4;     // base row in tile (4 consecutive rows)
    int tc = (tid >> 4) * 8;     // base col (8 consecutive cols)

    size_t r0 = (size_t)min(row0 + tr + 0, n - 1);
    size_t r1 = (size_t)min(row0 + tr + 1, n - 1);
    size_t r2 = (size_t)min(row0 + tr + 2, n - 1);
    size_t r3 = (size_t)min(row0 + tr + 3, n - 1);

    float acc[4][8];
#pragma unroll
    for (int r = 0; r < 4; ++r)
#pragma unroll
        for (int c = 0; c < 8; ++c) acc[r][c] = 0.0f;

    for (int k = 0; k < 128; k += 4) {
        float av[4][4];
        *(float4*)av[0] = *(const float4*)(A + r0 * 128 + k);
        *(float4*)av[1] = *(const float4*)(A + r1 * 128 + k);
        *(float4*)av[2] = *(const float4*)(A + r2 * 128 + k);
        *(float4*)av[3] = *(const float4*)(A + r3 * 128 + k);
#pragma unroll
        for (int kk = 0; kk < 4; ++kk) {
            float wv[8];
            *(float4*)&wv[0] = *(const float4*)&Wl[(k + kk) * 128 + tc];
            *(float4*)&wv[4] = *(const float4*)&Wl[(k + kk) * 128 + tc + 4];
#pragma unroll
            for (int r = 0; r < 4; ++r)
#pragma unroll
                for (int c = 0; c < 8; ++c) acc[r][c] += av[r][kk] * wv[c];
        }
    }

    float bv[8];
    if (bias) {
        *(float4*)&bv[0] = *(const float4*)&bias[tc];
        *(float4*)&bv[4] = *(const float4*)&bias[tc + 4];
    } else {
#pragma unroll
        for (int c = 0; c < 8; ++c) bv[c] = 0.0f;
    }

#pragma unroll
    for (int r = 0; r < 4; ++r) {
        int gr = row0 + tr + r;
        if (gr < n) {
            float o[8];
#pragma unroll
            for (int c = 0; c < 8; ++c) o[c] = acc[r][c] + bv[c];
            if (BF16OUT) {
                uint4 pk;
                pk.x = f2bf(o[0]) | (f2bf(o[1]) << 16);
                pk.y = f2bf(o[2]) | (f2bf(o[3]) << 16);
                pk.z = f2bf(o[4]) | (f2bf(o[5]) << 16);
                pk.w = f2bf(o[6]) | (f2bf(o[7]) << 16);
                *(uint4*)((unsigned*)C + (size_t)gr * 64 + (tc >> 1)) = pk;
            } else {
                *(float4*)((float*)C + (size_t)gr * 128 + tc)     = *(float4*)&o[0];
                *(float4*)((float*)C + (size_t)gr * 128 + tc + 4) = *(float4*)&o[4];
            }
        }
    }
}

// ---------- aggregation: one wave per destination node, bf16 gather ----------
// t packed bf16: row = 64 dwords, lane reads 1 dword = 2 features.
// out[i] = bias + dinv[i]^2 * t[i] + sum_e norm_e * t[src_e]
// FINAL: fuse out = sigmoid(dot(agg+bias, W2) + b2), one scalar per node.
template<bool FINAL>
__global__ __launch_bounds__(256) void aggregate_kernel(const unsigned* __restrict__ tb,
                                                        const int* __restrict__ row_ptr,
                                                        const int* __restrict__ esrc,
                                                        const float* __restrict__ enorm,
                                                        const float* __restrict__ dinv,
                                                        const float* __restrict__ bias,
                                                        const float* __restrict__ W2,
                                                        const float* __restrict__ b2,
                                                        float* __restrict__ out, int n) {
    int wid  = (int)((blockIdx.x * (size_t)blockDim.x + threadIdx.x) >> 6);
    int lane = threadIdx.x & 63;
    if (wid >= n) return;

    float di = dinv[wid];
    float sn = di * di;                       // self-loop norm = 1/deg
    unsigned ts = tb[(size_t)wid * 64 + lane];
    float accx = sn * bf_lo(ts), accy = sn * bf_hi(ts);

    int start = row_ptr[wid], end = row_ptr[wid + 1];
    for (int base = start; base < end; base += 64) {
        int rem = end - base;
        int s = 0; float w = 0.0f;
        if (lane < rem) { s = esrc[base + lane]; w = enorm[base + lane]; }
        int m = rem < 64 ? rem : 64;
#pragma unroll 4
        for (int j = 0; j < m; ++j) {
            int   sj = __shfl(s, j);
            float wj = __shfl(w, j);
            unsigned u = tb[(size_t)sj * 64 + lane];
            accx += wj * bf_lo(u);
            accy += wj * bf_hi(u);
        }
    }
    float2 bb = ((const float2*)bias)[lane];
    float ox = accx + bb.x, oy = accy + bb.y;
    if (FINAL) {
        float2 wv = ((const float2*)W2)[lane];
        float d = ox * wv.x + oy * wv.y;
#pragma unroll
        for (int off = 32; off > 0; off >>= 1) d += __shfl_down(d, off);
        if (lane == 0) out[wid] = 1.0f / (1.0f + expf(-(d + b2[0])));
    } else {
        float2 o; o.x = ox; o.y = oy;
        ((float2*)out)[(size_t)wid * 64 + lane] = o;
    }
}

extern "C" void kernel_launch(void* const* d_in, const int* in_sizes, int n_in,
                              void* d_out, int out_size, void* d_ws, size_t ws_size,
                              hipStream_t stream) {
    const float* x  = (const float*)d_in[0];
    const int*   ei = (const int*)d_in[1];   // [2, E] int32
    const float* ea = (const float*)d_in[2]; // [E]
    const float* W1 = (const float*)d_in[3];
    const float* b1 = (const float*)d_in[4];
    const float* Wg = (const float*)d_in[5]; // [3,128,128]
    const float* bg = (const float*)d_in[6]; // [3,128]
    const float* W2 = (const float*)d_in[7]; // [128]
    const float* b2 = (const float*)d_in[8]; // [1]

    const int N = in_sizes[0] / 128;
    const int E = in_sizes[2];
    const int* row = ei;
    const int* col = ei + E;

    // workspace layout (16B-aligned chunks)
    char* p = (char*)d_ws;
    float*    hbuf = (float*)p;    p += (size_t)N * 128 * 4;
    unsigned* tbuf = (unsigned*)p; p += (size_t)N * 64 * 4;   // bf16-packed messages
    float* deg  = (float*)p; p += (size_t)N * 4;
    float* dinv = (float*)p; p += (size_t)N * 4;
    int* cnt     = (int*)p;  p += (size_t)N * 4;
    int* row_ptr = (int*)p;  p += (size_t)(N + 1) * 4 + 12;
    int* cursor  = (int*)p;  p += (size_t)N * 4;
    int* bsum    = (int*)p;  p += 256 * 4;
    int* esrc    = (int*)p;  p += (size_t)E * 4;
    float* enorm = (float*)p;

    dim3 b256(256);
    int nblk = (N + 1023) / 1024;   // 98 for N=100000 (scan2 handles <=256)

    init_kernel   <<<(N + 255) / 256, b256, 0, stream>>>(deg, cnt, N);
    histo_kernel  <<<(E + 255) / 256, b256, 0, stream>>>(col, ea, deg, cnt, E);
    scan1_kernel  <<<nblk, b256, 0, stream>>>(cnt, bsum, N);
    scan2_kernel  <<<1, b256, 0, stream>>>(bsum, nblk);
    scan3_kernel  <<<nblk, b256, 0, stream>>>(cnt, bsum, row_ptr, cursor, N, nblk);
    prep_kernel   <<<(N + 255) / 256, b256, 0, stream>>>(deg, dinv, N);
    scatter_kernel<<<(E + 255) / 256, b256, 0, stream>>>(row, col, ea, dinv, cursor, esrc, enorm, E);

    int gemm_blocks = (N + 63) / 64;
    int wave_blocks = (int)(((size_t)N * 64 + 255) / 256);

    gemm128_kernel<false><<<gemm_blocks, b256, 0, stream>>>(x, W1, b1, hbuf, N);
    for (int l = 0; l < 3; ++l) {
        gemm128_kernel<true><<<gemm_blocks, b256, 0, stream>>>(hbuf, Wg + (size_t)l * 128 * 128,
                                                               nullptr, tbuf, N);
        if (l < 2) {
            aggregate_kernel<false><<<wave_blocks, b256, 0, stream>>>(
                tbuf, row_ptr, esrc, enorm, dinv, bg + (size_t)l * 128,
                nullptr, nullptr, hbuf, N);
        } else {
            aggregate_kernel<true><<<wave_blocks, b256, 0, stream>>>(
                tbuf, row_ptr, esrc, enorm, dinv, bg + (size_t)l * 128,
                W2, b2, (float*)d_out, N);
        }
    }
}

// Round 3
// 571.212 us; speedup vs baseline: 2.3640x; 1.9548x over previous
//
#include <hip/hip_runtime.h>
#include <cstdint>
#include <cstddef>

// SimpleGCN: h = x@W1+b1; 3x GCNConv(sym-norm adj w/ self loops); sigmoid(h@W2+b2)
// N=100000, d=128, E=1.6M.
// R3: (a) histo = single packed u64 atomic/edge (count<<40 | fix24(ew)),
//     (b) barrier-free MFMA bf16 GEMM (A+B direct from global, no LDS),
//     (c) aggregate: merged uint2 edge records + 8-wide batched gather.

typedef __attribute__((ext_vector_type(8))) short bf16x8;
typedef __attribute__((ext_vector_type(4))) float f32x4;

// ---------- bf16 helpers (packed dword: low 16 bits = element 0) ----------
__device__ __forceinline__ unsigned f2bf(float f) {      // RNE float->bf16 bits
    unsigned u = __float_as_uint(f);
    u += 0x7fffu + ((u >> 16) & 1u);
    return u >> 16;
}
__device__ __forceinline__ float bf_lo(unsigned p) { return __uint_as_float(p << 16); }
__device__ __forceinline__ float bf_hi(unsigned p) { return __uint_as_float(p & 0xffff0000u); }

// ---------- degree histogram: ONE u64 atomic per edge ----------
// packed[c] = (in_count << 40) | sum(ew * 2^24)   (sum < 2^40 for deg < 64k)
__global__ void histo_kernel(const int* __restrict__ col, const float* __restrict__ ew,
                             unsigned long long* __restrict__ packed, int E) {
    int e = blockIdx.x * blockDim.x + threadIdx.x;
    if (e < E) {
        int c = col[e];
        unsigned long long v = (1ull << 40) |
            (unsigned long long)(unsigned)(ew[e] * 16777216.0f);
        atomicAdd(&packed[c], v);
    }
}

// ---------- 3-phase exclusive scan over packed counts ----------
__global__ __launch_bounds__(256) void scan1_kernel(const unsigned long long* __restrict__ packed,
                                                    int* __restrict__ bsum, int n) {
    __shared__ int s[256];
    int b = blockIdx.x, t = threadIdx.x;
    int base = b * 1024 + t * 4;
    int acc = 0;
#pragma unroll
    for (int i = 0; i < 4; ++i)
        if (base + i < n) acc += (int)(packed[base + i] >> 40);
    s[t] = acc;
    __syncthreads();
    for (int off = 128; off > 0; off >>= 1) {
        if (t < off) s[t] += s[t + off];
        __syncthreads();
    }
    if (t == 0) bsum[b] = s[0];
}

__global__ __launch_bounds__(256) void scan2_kernel(int* __restrict__ bsum, int nblk) {
    __shared__ int s[256];
    int t = threadIdx.x;
    int v = (t < nblk) ? bsum[t] : 0;
    s[t] = v;
    __syncthreads();
    for (int off = 1; off < 256; off <<= 1) {
        int u = (t >= off) ? s[t - off] : 0;
        __syncthreads();
        s[t] += u;
        __syncthreads();
    }
    if (t < nblk) bsum[t] = s[t] - v;   // exclusive
}

// phase 3: row_ptr + cursor + dinv (prep folded in)
__global__ __launch_bounds__(256) void scan3_kernel(const unsigned long long* __restrict__ packed,
                                                    const int* __restrict__ boff,
                                                    int* __restrict__ row_ptr,
                                                    int* __restrict__ cursor,
                                                    float* __restrict__ dinv,
                                                    int n, int nblk) {
    __shared__ int s[256];
    int b = blockIdx.x, t = threadIdx.x;
    int base = b * 1024 + t * 4;
    int v[4];
#pragma unroll
    for (int i = 0; i < 4; ++i) {
        unsigned long long p = (base + i < n) ? packed[base + i] : 0ull;
        v[i] = (int)(p >> 40);
        if (base + i < n) {
            float deg = 1.0f + (float)(p & 0xFFFFFFFFFFull) * (1.0f / 16777216.0f);
            dinv[base + i] = rsqrtf(deg);
        }
    }
    s[t] = v[0] + v[1] + v[2] + v[3];
    __syncthreads();
    for (int off = 1; off < 256; off <<= 1) {
        int u = (t >= off) ? s[t - off] : 0;
        __syncthreads();
        s[t] += u;
        __syncthreads();
    }
    int run = boff[b] + ((t == 0) ? 0 : s[t - 1]);
#pragma unroll
    for (int i = 0; i < 4; ++i) {
        if (base + i < n) { row_ptr[base + i] = run; cursor[base + i] = run; run += v[i]; }
    }
    if (b == nblk - 1 && t == 255) row_ptr[n] = boff[b] + s[255];
}

// ---------- scatter: CSR edge records, one dwordx2 store ----------
__global__ void scatter_kernel(const int* __restrict__ row, const int* __restrict__ col,
                               const float* __restrict__ ew, const float* __restrict__ dinv,
                               int* __restrict__ cursor, uint2* __restrict__ edata, int E) {
    int e = blockIdx.x * blockDim.x + threadIdx.x;
    if (e < E) {
        int r = row[e], c = col[e];
        int pos = atomicAdd(&cursor[c], 1);
        float nrm = dinv[r] * ew[e] * dinv[c];
        edata[pos] = make_uint2((unsigned)r, __float_as_uint(nrm));
    }
}

// ---------- weight prep: Wt[l][n][k] = bf16(W_l[k][n]), l=0:W1, 1..3:Wg ----------
__global__ void prep_weights_kernel(const float* __restrict__ W1, const float* __restrict__ Wg,
                                    unsigned short* __restrict__ Wt) {
    int idx = blockIdx.x * blockDim.x + threadIdx.x;   // 0..65535
    int l = idx >> 14, n = (idx >> 7) & 127, k = idx & 127;
    const float* W = (l == 0) ? W1 : (Wg + (size_t)(l - 1) * 16384);
    Wt[idx] = (unsigned short)f2bf(W[k * 128 + n]);
}

// ---------- MFMA GEMM: C[n x 128](bf16) = A[n x 128] @ W (+bias) ----------
// No LDS, no barriers: per wave 32x128 tile. A elements are consumed by exactly
// one lane (N=128 fits one wave's col coverage); B (Wt) is L1/L2-resident.
// mfma_f32_16x16x32_bf16: A[m=lane&15][k=(lane>>4)*8+j]; B[k][n=lane&15] same k-map;
// C/D col=lane&15, row=(lane>>4)*4+reg.
template<bool A_FP32>
__global__ __launch_bounds__(256) void gemm_mfma_kernel(const void* __restrict__ Av,
                                                        const unsigned short* __restrict__ Wt,
                                                        const float* __restrict__ bias,
                                                        unsigned short* __restrict__ C, int n) {
    int tid = threadIdx.x;
    int wave = tid >> 6, lane = tid & 63;
    int lm = lane & 15, g = lane >> 4;
    int m_base = blockIdx.x * 128 + wave * 32;

    f32x4 acc[2][8];
#pragma unroll
    for (int rt = 0; rt < 2; ++rt)
#pragma unroll
        for (int ct = 0; ct < 8; ++ct) acc[rt][ct] = (f32x4){0.f, 0.f, 0.f, 0.f};

    size_t rowA[2];
    rowA[0] = (size_t)min(m_base + lm, n - 1);        // clamp: input array is exact-size
    rowA[1] = (size_t)min(m_base + 16 + lm, n - 1);

#pragma unroll
    for (int kc = 0; kc < 4; ++kc) {
        int k0 = kc * 32 + g * 8;
        bf16x8 a[2];
        if (A_FP32) {
            const float* A = (const float*)Av;
#pragma unroll
            for (int rt = 0; rt < 2; ++rt) {
                const float* p = A + rowA[rt] * 128 + k0;
                float f[8];
                *(float4*)&f[0] = *(const float4*)p;
                *(float4*)&f[4] = *(const float4*)(p + 4);
                short sv[8];
#pragma unroll
                for (int j = 0; j < 8; ++j) sv[j] = (short)f2bf(f[j]);
                a[rt] = *(bf16x8*)sv;
            }
        } else {
            const unsigned short* A = (const unsigned short*)Av;
#pragma unroll
            for (int rt = 0; rt < 2; ++rt)
                a[rt] = *(const bf16x8*)(A + rowA[rt] * 128 + k0);
        }
        bf16x8 b[8];
#pragma unroll
        for (int ct = 0; ct < 8; ++ct)
            b[ct] = *(const bf16x8*)(Wt + (ct * 16 + lm) * 128 + k0);
#pragma unroll
        for (int ct = 0; ct < 8; ++ct) {
            acc[0][ct] = __builtin_amdgcn_mfma_f32_16x16x32_bf16(a[0], b[ct], acc[0][ct], 0, 0, 0);
            acc[1][ct] = __builtin_amdgcn_mfma_f32_16x16x32_bf16(a[1], b[ct], acc[1][ct], 0, 0, 0);
        }
    }

#pragma unroll
    for (int rt = 0; rt < 2; ++rt) {
#pragma unroll
        for (int r = 0; r < 4; ++r) {
            int grow = m_base + rt * 16 + g * 4 + r;
            if (grow < n) {
#pragma unroll
                for (int ct = 0; ct < 8; ++ct) {
                    float v = acc[rt][ct][r];
                    if (bias) v += bias[ct * 16 + lm];
                    C[(size_t)grow * 128 + ct * 16 + lm] = (unsigned short)f2bf(v);
                }
            }
        }
    }
}

// ---------- aggregation: one wave per dest node, bf16 gather, 8-wide ILP ----------
// out[i] = bias + dinv[i]^2 * t[i] + sum_e norm_e * t[src_e]
// FINAL: fused out = sigmoid(dot(agg+bias, W2) + b2)
template<bool FINAL>
__global__ __launch_bounds__(256) void aggregate_kernel(const unsigned* __restrict__ tb,
                                                        const int* __restrict__ row_ptr,
                                                        const uint2* __restrict__ edata,
                                                        const float* __restrict__ dinv,
                                                        const float* __restrict__ bias,
                                                        const float* __restrict__ W2,
                                                        const float* __restrict__ b2,
                                                        void* __restrict__ out, int n) {
    int wid  = (int)((blockIdx.x * (size_t)blockDim.x + threadIdx.x) >> 6);
    int lane = threadIdx.x & 63;
    if (wid >= n) return;

    float di = dinv[wid];
    float sn = di * di;                       // self-loop norm = 1/deg
    unsigned ts = tb[(size_t)wid * 64 + lane];
    float accx = sn * bf_lo(ts), accy = sn * bf_hi(ts);

    int start = row_ptr[wid], end = row_ptr[wid + 1];
    for (int base = start; base < end; base += 64) {
        int rem = end - base;
        int m = rem < 64 ? rem : 64;
        uint2 ed = edata[base + lane];        // edata is padded by 64 records; lanes>=rem unused
        int sv = (int)ed.x;
        float wv = __uint_as_float(ed.y);
        int j = 0;
        for (; j + 8 <= m; j += 8) {
            int s_[8]; float w_[8]; unsigned u_[8];
#pragma unroll
            for (int k = 0; k < 8; ++k) { s_[k] = __shfl(sv, j + k); w_[k] = __shfl(wv, j + k); }
#pragma unroll
            for (int k = 0; k < 8; ++k) u_[k] = tb[(size_t)s_[k] * 64 + lane];
#pragma unroll
            for (int k = 0; k < 8; ++k) { accx += w_[k] * bf_lo(u_[k]); accy += w_[k] * bf_hi(u_[k]); }
        }
        for (; j < m; ++j) {
            int   sj = __shfl(sv, j);
            float wj = __shfl(wv, j);
            unsigned u = tb[(size_t)sj * 64 + lane];
            accx += wj * bf_lo(u);
            accy += wj * bf_hi(u);
        }
    }
    float2 bb = ((const float2*)bias)[lane];
    float ox = accx + bb.x, oy = accy + bb.y;
    if (FINAL) {
        float2 wv2 = ((const float2*)W2)[lane];
        float d = ox * wv2.x + oy * wv2.y;
#pragma unroll
        for (int off = 32; off > 0; off >>= 1) d += __shfl_down(d, off);
        if (lane == 0) ((float*)out)[wid] = 1.0f / (1.0f + expf(-(d + b2[0])));
    } else {
        ((unsigned*)out)[(size_t)wid * 64 + lane] = f2bf(ox) | (f2bf(oy) << 16);
    }
}

static inline char* align16(char* p) { return (char*)(((uintptr_t)p + 15) & ~(uintptr_t)15); }

extern "C" void kernel_launch(void* const* d_in, const int* in_sizes, int n_in,
                              void* d_out, int out_size, void* d_ws, size_t ws_size,
                              hipStream_t stream) {
    const float* x  = (const float*)d_in[0];
    const int*   ei = (const int*)d_in[1];   // [2, E] int32
    const float* ea = (const float*)d_in[2]; // [E]
    const float* W1 = (const float*)d_in[3];
    const float* b1 = (const float*)d_in[4];
    const float* Wg = (const float*)d_in[5]; // [3,128,128]
    const float* bg = (const float*)d_in[6]; // [3,128]
    const float* W2 = (const float*)d_in[7]; // [128]
    const float* b2 = (const float*)d_in[8]; // [1]

    const int N = in_sizes[0] / 128;
    const int E = in_sizes[2];
    const int Npad = (N + 127) & ~127;
    const int* row = ei;
    const int* col = ei + E;

    // workspace layout
    char* p = (char*)d_ws;
    unsigned short* hbuf = (unsigned short*)p; p += (size_t)Npad * 128 * 2;  // bf16 state
    unsigned short* tbuf = (unsigned short*)p; p += (size_t)Npad * 128 * 2;  // bf16 messages
    unsigned short* wbuf = (unsigned short*)p; p += 4 * 16384 * 2;           // bf16 W^T x4
    p = align16(p);
    unsigned long long* packed = (unsigned long long*)p; p += (size_t)N * 8;
    float* dinv   = (float*)p; p += (size_t)N * 4;
    int* row_ptr  = (int*)p;   p += (size_t)(N + 1) * 4; p = align16(p);
    int* cursor   = (int*)p;   p += (size_t)N * 4;
    int* bsum     = (int*)p;   p += 256 * 4;
    uint2* edata  = (uint2*)p;                            // E + 64 records (padded read)

    dim3 b256(256);
    int nblk = (N + 1023) / 1024;   // 98 (scan2 handles <=256)

    hipMemsetAsync(packed, 0, (size_t)N * 8, stream);
    prep_weights_kernel<<<256, b256, 0, stream>>>(W1, Wg, wbuf);
    histo_kernel  <<<(E + 255) / 256, b256, 0, stream>>>(col, ea, packed, E);
    scan1_kernel  <<<nblk, b256, 0, stream>>>(packed, bsum, N);
    scan2_kernel  <<<1, b256, 0, stream>>>(bsum, nblk);
    scan3_kernel  <<<nblk, b256, 0, stream>>>(packed, bsum, row_ptr, cursor, dinv, N, nblk);
    scatter_kernel<<<(E + 255) / 256, b256, 0, stream>>>(row, col, ea, dinv, cursor, edata, E);

    int gemm_blocks = Npad / 128;
    int wave_blocks = (int)(((size_t)N * 64 + 255) / 256);

    gemm_mfma_kernel<true><<<gemm_blocks, b256, 0, stream>>>(x, wbuf, b1, hbuf, N);
    for (int l = 0; l < 3; ++l) {
        gemm_mfma_kernel<false><<<gemm_blocks, b256, 0, stream>>>(hbuf, wbuf + (size_t)(l + 1) * 16384,
                                                                  nullptr, tbuf, N);
        if (l < 2) {
            aggregate_kernel<false><<<wave_blocks, b256, 0, stream>>>(
                (const unsigned*)tbuf, row_ptr, edata, dinv, bg + (size_t)l * 128,
                nullptr, nullptr, hbuf, N);
        } else {
            aggregate_kernel<true><<<wave_blocks, b256, 0, stream>>>(
                (const unsigned*)tbuf, row_ptr, edata, dinv, bg + (size_t)l * 128,
                W2, b2, d_out, N);
        }
    }
}

// Round 4
// 518.439 us; speedup vs baseline: 2.6047x; 1.1018x over previous
//
#include <hip/hip_runtime.h>
#include <cstdint>
#include <cstddef>

// SimpleGCN: h = x@W1+b1; 3x GCNConv(sym-norm adj w/ self loops); sigmoid(h@W2+b2)
// N=100000, d=128, E=1.6M.
// R4: (a) edge rank harvested from histo atomic return -> scatter has NO atomics
//     (R3 counters: WRITE_SIZE ~= E*64B => atomics write through 64B lines; the
//     scatter's cost was its cursor atomics, not the payload),
//     (b) 4B packed edge records (src:17b | norm:15b bf16-no-sign),
//     (c) CSR buckets padded to x8 (pad = src 0 / norm 0) -> mask-free 16/8-wide
//     batched gather in aggregate.

typedef __attribute__((ext_vector_type(8))) short bf16x8;
typedef __attribute__((ext_vector_type(4))) float f32x4;

// ---------- bf16 helpers (packed dword: low 16 bits = element 0) ----------
__device__ __forceinline__ unsigned f2bf(float f) {      // RNE float->bf16 bits
    unsigned u = __float_as_uint(f);
    u += 0x7fffu + ((u >> 16) & 1u);
    return u >> 16;
}
__device__ __forceinline__ float bf_lo(unsigned p) { return __uint_as_float(p << 16); }
__device__ __forceinline__ float bf_hi(unsigned p) { return __uint_as_float(p & 0xffff0000u); }

// ---------- histo + rank: ONE u64 atomic per edge, rank = returned old count ----------
// packed[c] = (in_count << 40) | sum(ew * 2^24)   (sum < 2^40 for deg < 64k)
__global__ void histo_kernel(const int* __restrict__ col, const float* __restrict__ ew,
                             unsigned long long* __restrict__ packed,
                             unsigned short* __restrict__ rank, int E) {
    int e = blockIdx.x * blockDim.x + threadIdx.x;
    if (e < E) {
        int c = col[e];
        unsigned long long v = (1ull << 40) |
            (unsigned long long)(unsigned)(ew[e] * 16777216.0f);
        unsigned long long old = atomicAdd(&packed[c], v);
        rank[e] = (unsigned short)(old >> 40);
    }
}

// ---------- 3-phase exclusive scan over PADDED counts (round up to x8) ----------
__global__ __launch_bounds__(256) void scan1_kernel(const unsigned long long* __restrict__ packed,
                                                    int* __restrict__ bsum, int n) {
    __shared__ int s[256];
    int b = blockIdx.x, t = threadIdx.x;
    int base = b * 1024 + t * 4;
    int acc = 0;
#pragma unroll
    for (int i = 0; i < 4; ++i)
        if (base + i < n) acc += ((int)(packed[base + i] >> 40) + 7) & ~7;
    s[t] = acc;
    __syncthreads();
    for (int off = 128; off > 0; off >>= 1) {
        if (t < off) s[t] += s[t + off];
        __syncthreads();
    }
    if (t == 0) bsum[b] = s[0];
}

__global__ __launch_bounds__(256) void scan2_kernel(int* __restrict__ bsum, int nblk) {
    __shared__ int s[256];
    int t = threadIdx.x;
    int v = (t < nblk) ? bsum[t] : 0;
    s[t] = v;
    __syncthreads();
    for (int off = 1; off < 256; off <<= 1) {
        int u = (t >= off) ? s[t - off] : 0;
        __syncthreads();
        s[t] += u;
        __syncthreads();
    }
    if (t < nblk) bsum[t] = s[t] - v;   // exclusive
}

// phase 3: row_ptr (padded) + dinv
__global__ __launch_bounds__(256) void scan3_kernel(const unsigned long long* __restrict__ packed,
                                                    const int* __restrict__ boff,
                                                    int* __restrict__ row_ptr,
                                                    float* __restrict__ dinv,
                                                    int n, int nblk) {
    __shared__ int s[256];
    int b = blockIdx.x, t = threadIdx.x;
    int base = b * 1024 + t * 4;
    int v[4];
#pragma unroll
    for (int i = 0; i < 4; ++i) {
        unsigned long long p = (base + i < n) ? packed[base + i] : 0ull;
        v[i] = (((int)(p >> 40)) + 7) & ~7;   // padded count
        if (base + i < n) {
            float deg = 1.0f + (float)(p & 0xFFFFFFFFFFull) * (1.0f / 16777216.0f);
            dinv[base + i] = rsqrtf(deg);
        }
    }
    s[t] = v[0] + v[1] + v[2] + v[3];
    __syncthreads();
    for (int off = 1; off < 256; off <<= 1) {
        int u = (t >= off) ? s[t - off] : 0;
        __syncthreads();
        s[t] += u;
        __syncthreads();
    }
    int run = boff[b] + ((t == 0) ? 0 : s[t - 1]);
#pragma unroll
    for (int i = 0; i < 4; ++i) {
        if (base + i < n) { row_ptr[base + i] = run; run += v[i]; }
    }
    if (b == nblk - 1 && t == 255) row_ptr[n] = boff[b] + s[255];
}

// ---------- scatter (NO atomics): pos = row_ptr[c] + rank[e] ----------
// record = (src << 15) | (bf16(norm) & 0x7fff); norm > 0 so sign bit unused.
__global__ void scatter_kernel(const int* __restrict__ row, const int* __restrict__ col,
                               const float* __restrict__ ew, const float* __restrict__ dinv,
                               const int* __restrict__ row_ptr,
                               const unsigned short* __restrict__ rank,
                               unsigned* __restrict__ edata, int E) {
    int e = blockIdx.x * blockDim.x + threadIdx.x;
    if (e < E) {
        int r = row[e], c = col[e];
        float nrm = dinv[r] * ew[e] * dinv[c];
        int pos = row_ptr[c] + (int)rank[e];
        edata[pos] = ((unsigned)r << 15) | (f2bf(nrm) & 0x7fffu);
    }
}

// ---------- weight prep: Wt[l][n][k] = bf16(W_l[k][n]), l=0:W1, 1..3:Wg ----------
__global__ void prep_weights_kernel(const float* __restrict__ W1, const float* __restrict__ Wg,
                                    unsigned short* __restrict__ Wt) {
    int idx = blockIdx.x * blockDim.x + threadIdx.x;   // 0..65535
    int l = idx >> 14, n = (idx >> 7) & 127, k = idx & 127;
    const float* W = (l == 0) ? W1 : (Wg + (size_t)(l - 1) * 16384);
    Wt[idx] = (unsigned short)f2bf(W[k * 128 + n]);
}

// ---------- MFMA GEMM: C[n x 128](bf16) = A[n x 128] @ W (+bias) ----------
// No LDS, no barriers: per wave 32x128 tile; B (Wt) is L1/L2-resident.
template<bool A_FP32>
__global__ __launch_bounds__(256) void gemm_mfma_kernel(const void* __restrict__ Av,
                                                        const unsigned short* __restrict__ Wt,
                                                        const float* __restrict__ bias,
                                                        unsigned short* __restrict__ C, int n) {
    int tid = threadIdx.x;
    int wave = tid >> 6, lane = tid & 63;
    int lm = lane & 15, g = lane >> 4;
    int m_base = blockIdx.x * 128 + wave * 32;

    f32x4 acc[2][8];
#pragma unroll
    for (int rt = 0; rt < 2; ++rt)
#pragma unroll
        for (int ct = 0; ct < 8; ++ct) acc[rt][ct] = (f32x4){0.f, 0.f, 0.f, 0.f};

    size_t rowA[2];
    rowA[0] = (size_t)min(m_base + lm, n - 1);
    rowA[1] = (size_t)min(m_base + 16 + lm, n - 1);

#pragma unroll
    for (int kc = 0; kc < 4; ++kc) {
        int k0 = kc * 32 + g * 8;
        bf16x8 a[2];
        if (A_FP32) {
            const float* A = (const float*)Av;
#pragma unroll
            for (int rt = 0; rt < 2; ++rt) {
                const float* p = A + rowA[rt] * 128 + k0;
                float f[8];
                *(float4*)&f[0] = *(const float4*)p;
                *(float4*)&f[4] = *(const float4*)(p + 4);
                short sv[8];
#pragma unroll
                for (int j = 0; j < 8; ++j) sv[j] = (short)f2bf(f[j]);
                a[rt] = *(bf16x8*)sv;
            }
        } else {
            const unsigned short* A = (const unsigned short*)Av;
#pragma unroll
            for (int rt = 0; rt < 2; ++rt)
                a[rt] = *(const bf16x8*)(A + rowA[rt] * 128 + k0);
        }
        bf16x8 b[8];
#pragma unroll
        for (int ct = 0; ct < 8; ++ct)
            b[ct] = *(const bf16x8*)(Wt + (ct * 16 + lm) * 128 + k0);
#pragma unroll
        for (int ct = 0; ct < 8; ++ct) {
            acc[0][ct] = __builtin_amdgcn_mfma_f32_16x16x32_bf16(a[0], b[ct], acc[0][ct], 0, 0, 0);
            acc[1][ct] = __builtin_amdgcn_mfma_f32_16x16x32_bf16(a[1], b[ct], acc[1][ct], 0, 0, 0);
        }
    }

#pragma unroll
    for (int rt = 0; rt < 2; ++rt) {
#pragma unroll
        for (int r = 0; r < 4; ++r) {
            int grow = m_base + rt * 16 + g * 4 + r;
            if (grow < n) {
#pragma unroll
                for (int ct = 0; ct < 8; ++ct) {
                    float v = acc[rt][ct][r];
                    if (bias) v += bias[ct * 16 + lm];
                    C[(size_t)grow * 128 + ct * 16 + lm] = (unsigned short)f2bf(v);
                }
            }
        }
    }
}

// ---------- aggregation: one wave per dest node, mask-free batched gather ----------
// bucket size is a multiple of 8; pad records are (src=0, norm=0) -> harmless.
template<bool FINAL>
__global__ __launch_bounds__(256) void aggregate_kernel(const unsigned* __restrict__ tb,
                                                        const int* __restrict__ row_ptr,
                                                        const unsigned* __restrict__ edata,
                                                        const float* __restrict__ dinv,
                                                        const float* __restrict__ bias,
                                                        const float* __restrict__ W2,
                                                        const float* __restrict__ b2,
                                                        void* __restrict__ out, int n) {
    int wid  = (int)((blockIdx.x * (size_t)blockDim.x + threadIdx.x) >> 6);
    int lane = threadIdx.x & 63;
    if (wid >= n) return;

    float di = dinv[wid];
    float sn = di * di;                       // self-loop norm = 1/deg
    unsigned ts = tb[(size_t)wid * 64 + lane];
    float accx = sn * bf_lo(ts), accy = sn * bf_hi(ts);

    int start = row_ptr[wid], end = row_ptr[wid + 1];
    for (int base = start; base < end; base += 64) {
        unsigned ed = edata[base + lane];     // over-read into next buckets is harmless
        int m = end - base; if (m > 64) m = 64;
        int j = 0;
        for (; j + 16 <= m; j += 16) {
            unsigned p[16], u[16];
#pragma unroll
            for (int k = 0; k < 16; ++k) p[k] = __shfl(ed, j + k);
#pragma unroll
            for (int k = 0; k < 16; ++k) u[k] = tb[(size_t)(p[k] >> 15) * 64 + lane];
#pragma unroll
            for (int k = 0; k < 16; ++k) {
                float w = __uint_as_float((p[k] & 0x7fffu) << 16);
                accx += w * bf_lo(u[k]);
                accy += w * bf_hi(u[k]);
            }
        }
        for (; j < m; j += 8) {               // m is a multiple of 8: no scalar tail
            unsigned p[8], u[8];
#pragma unroll
            for (int k = 0; k < 8; ++k) p[k] = __shfl(ed, j + k);
#pragma unroll
            for (int k = 0; k < 8; ++k) u[k] = tb[(size_t)(p[k] >> 15) * 64 + lane];
#pragma unroll
            for (int k = 0; k < 8; ++k) {
                float w = __uint_as_float((p[k] & 0x7fffu) << 16);
                accx += w * bf_lo(u[k]);
                accy += w * bf_hi(u[k]);
            }
        }
    }
    float2 bb = ((const float2*)bias)[lane];
    float ox = accx + bb.x, oy = accy + bb.y;
    if (FINAL) {
        float2 wv2 = ((const float2*)W2)[lane];
        float d = ox * wv2.x + oy * wv2.y;
#pragma unroll
        for (int off = 32; off > 0; off >>= 1) d += __shfl_down(d, off);
        if (lane == 0) ((float*)out)[wid] = 1.0f / (1.0f + expf(-(d + b2[0])));
    } else {
        ((unsigned*)out)[(size_t)wid * 64 + lane] = f2bf(ox) | (f2bf(oy) << 16);
    }
}

static inline char* align16(char* p) { return (char*)(((uintptr_t)p + 15) & ~(uintptr_t)15); }

extern "C" void kernel_launch(void* const* d_in, const int* in_sizes, int n_in,
                              void* d_out, int out_size, void* d_ws, size_t ws_size,
                              hipStream_t stream) {
    const float* x  = (const float*)d_in[0];
    const int*   ei = (const int*)d_in[1];   // [2, E] int32
    const float* ea = (const float*)d_in[2]; // [E]
    const float* W1 = (const float*)d_in[3];
    const float* b1 = (const float*)d_in[4];
    const float* Wg = (const float*)d_in[5]; // [3,128,128]
    const float* bg = (const float*)d_in[6]; // [3,128]
    const float* W2 = (const float*)d_in[7]; // [128]
    const float* b2 = (const float*)d_in[8]; // [1]

    const int N = in_sizes[0] / 128;
    const int E = in_sizes[2];
    const int Npad = (N + 127) & ~127;
    const int* row = ei;
    const int* col = ei + E;

    // workspace layout
    char* p = (char*)d_ws;
    unsigned short* hbuf = (unsigned short*)p; p += (size_t)Npad * 128 * 2;  // bf16 state
    unsigned short* tbuf = (unsigned short*)p; p += (size_t)Npad * 128 * 2;  // bf16 messages
    unsigned short* wbuf = (unsigned short*)p; p += 4 * 16384 * 2;           // bf16 W^T x4
    p = align16(p);
    unsigned long long* packed = (unsigned long long*)p; p += (size_t)N * 8;
    float* dinv   = (float*)p; p += (size_t)N * 4;
    int* row_ptr  = (int*)p;   p += (size_t)(N + 1) * 4; p = align16(p);
    int* bsum     = (int*)p;   p += 256 * 4;
    unsigned short* rank = (unsigned short*)p; p += (size_t)E * 2; p = align16(p);
    unsigned* edata = (unsigned*)p;                    // E + 7N + 64 padded records
    size_t edata_n = (size_t)E + 7 * (size_t)N + 64;

    dim3 b256(256);
    int nblk = (N + 1023) / 1024;   // 98 (scan2 handles <=256)

    hipMemsetAsync(packed, 0, (size_t)N * 8, stream);
    hipMemsetAsync(edata, 0, edata_n * 4, stream);
    prep_weights_kernel<<<256, b256, 0, stream>>>(W1, Wg, wbuf);
    histo_kernel  <<<(E + 255) / 256, b256, 0, stream>>>(col, ea, packed, rank, E);
    scan1_kernel  <<<nblk, b256, 0, stream>>>(packed, bsum, N);
    scan2_kernel  <<<1, b256, 0, stream>>>(bsum, nblk);
    scan3_kernel  <<<nblk, b256, 0, stream>>>(packed, bsum, row_ptr, dinv, N, nblk);
    scatter_kernel<<<(E + 255) / 256, b256, 0, stream>>>(row, col, ea, dinv, row_ptr, rank, edata, E);

    int gemm_blocks = Npad / 128;
    int wave_blocks = (int)(((size_t)N * 64 + 255) / 256);

    gemm_mfma_kernel<true><<<gemm_blocks, b256, 0, stream>>>(x, wbuf, b1, hbuf, N);
    for (int l = 0; l < 3; ++l) {
        gemm_mfma_kernel<false><<<gemm_blocks, b256, 0, stream>>>(hbuf, wbuf + (size_t)(l + 1) * 16384,
                                                                  nullptr, tbuf, N);
        if (l < 2) {
            aggregate_kernel<false><<<wave_blocks, b256, 0, stream>>>(
                (const unsigned*)tbuf, row_ptr, edata, dinv, bg + (size_t)l * 128,
                nullptr, nullptr, hbuf, N);
        } else {
            aggregate_kernel<true><<<wave_blocks, b256, 0, stream>>>(
                (const unsigned*)tbuf, row_ptr, edata, dinv, bg + (size_t)l * 128,
                W2, b2, d_out, N);
        }
    }
}